// Round 1
// baseline (699.198 us; speedup 1.0000x reference)
//
#include <hip/hip_runtime.h>
#include <stdint.h>

// Problem constants (B=4, S=1536, D=2048, H=16, hd=128)
#define BB 4
#define SS 1536
#define DD 2048
#define HH 16
#define HD 128
#define BS (BB * SS)        // 6144 rows
#define N3 (3 * DD)         // 6144

typedef __bf16 bf16x8 __attribute__((ext_vector_type(8)));
typedef float f32x4 __attribute__((ext_vector_type(4)));

// ---------------------------------------------------------------------------
// async global->LDS (16B per lane; LDS dest = wave-uniform base + lane*16)
// ---------------------------------------------------------------------------
__device__ __forceinline__ void async16(const void* g, void* lds) {
  __builtin_amdgcn_global_load_lds(
      (const __attribute__((address_space(1))) unsigned int*)g,
      (__attribute__((address_space(3))) unsigned int*)lds, 16, 0, 0);
}

// ---------------------------------------------------------------------------
// cast fp32 -> bf16, 8 elems/thread
// ---------------------------------------------------------------------------
__global__ __launch_bounds__(256) void cast_bf16_kernel(
    const float* __restrict__ in, __bf16* __restrict__ out) {
  long i = ((long)blockIdx.x * 256 + threadIdx.x) * 8;
  float4 a = *(const float4*)(in + i);
  float4 b = *(const float4*)(in + i + 4);
  bf16x8 o;
  o[0] = (__bf16)a.x; o[1] = (__bf16)a.y; o[2] = (__bf16)a.z; o[3] = (__bf16)a.w;
  o[4] = (__bf16)b.x; o[5] = (__bf16)b.y; o[6] = (__bf16)b.z; o[7] = (__bf16)b.w;
  *(bf16x8*)(out + i) = o;
}

// ---------------------------------------------------------------------------
// transpose + cast: out[c][r] = (bf16)in[r][c].  R,C multiples of 32.
// ---------------------------------------------------------------------------
__global__ __launch_bounds__(256) void transpose_cast_kernel(
    const float* __restrict__ in, __bf16* __restrict__ out, int R, int C) {
  __shared__ __bf16 t[32][33];
  int tx = threadIdx.x & 31, ty = threadIdx.x >> 5;  // 32 x 8
  long r0 = (long)blockIdx.y * 32, c0 = (long)blockIdx.x * 32;
#pragma unroll
  for (int i = 0; i < 4; ++i)
    t[ty + i * 8][tx] = (__bf16)in[(r0 + ty + i * 8) * C + c0 + tx];
  __syncthreads();
#pragma unroll
  for (int i = 0; i < 4; ++i)
    out[(c0 + ty + i * 8) * R + r0 + tx] = t[tx][ty + i * 8];
}

// ---------------------------------------------------------------------------
// GEMM: C[M][N] = A[M][K] * Bt[N][K]^T + bias, bf16 inputs, MFMA 16x16x32.
// 128x128 tile / block(256)=4 waves, each wave 64x64 (4x4 16x16 tiles), BK=32.
// m97 structure: global_load_lds width-16 staging, 2-barrier K-loop.
// ---------------------------------------------------------------------------
__device__ __forceinline__ void store_val(__bf16* p, float v) { *p = (__bf16)v; }
__device__ __forceinline__ void store_val(float* p, float v) { *p = v; }

template <typename OutT>
__global__ __launch_bounds__(256, 2) void gemm_bt_kernel(
    const __bf16* __restrict__ A, const __bf16* __restrict__ Bt,
    const float* __restrict__ bias, OutT* __restrict__ C,
    int M, int N, int K) {
  __shared__ __attribute__((aligned(16))) __bf16 sA[128 * 32];
  __shared__ __attribute__((aligned(16))) __bf16 sB[128 * 32];
  const int tid = threadIdx.x;
  const int wave = tid >> 6, lane = tid & 63;
  const int quad = lane >> 4, l15 = lane & 15;
  const int bm = blockIdx.y * 128, bn = blockIdx.x * 128;
  const int wr = (wave >> 1) * 64, wc = (wave & 1) * 64;

  // staging: one inst = 16 rows x 32 cols (1KB); lane -> row=lane>>2, kchunk=lane&3
  const int srow = lane >> 2;
  const int scol = (lane & 3) * 8;
  const __bf16* Ap = A + (long)(bm + wave * 32 + srow) * K + scol;
  const __bf16* Bp = Bt + (long)(bn + wave * 32 + srow) * K + scol;
  __bf16* sAw = &sA[wave * 32 * 32];
  __bf16* sBw = &sB[wave * 32 * 32];

  f32x4 acc[4][4] = {};

  for (int k0 = 0; k0 < K; k0 += 32) {
    __syncthreads();
    async16(Ap + k0, sAw);
    async16(Ap + k0 + (long)16 * K, sAw + 16 * 32);
    async16(Bp + k0, sBw);
    async16(Bp + k0 + (long)16 * K, sBw + 16 * 32);
    __syncthreads();
    bf16x8 af[4], bfr[4];
#pragma unroll
    for (int i = 0; i < 4; ++i)
      af[i] = *(const bf16x8*)&sA[(wr + i * 16 + l15) * 32 + quad * 8];
#pragma unroll
    for (int i = 0; i < 4; ++i)
      bfr[i] = *(const bf16x8*)&sB[(wc + i * 16 + l15) * 32 + quad * 8];
#pragma unroll
    for (int i = 0; i < 4; ++i)
#pragma unroll
      for (int j = 0; j < 4; ++j)
        acc[i][j] = __builtin_amdgcn_mfma_f32_16x16x32_bf16(af[i], bfr[j],
                                                            acc[i][j], 0, 0, 0);
  }

  // epilogue: C/D layout col=lane&15, row=(lane>>4)*4+reg
#pragma unroll
  for (int i = 0; i < 4; ++i) {
    int row0 = bm + wr + i * 16 + quad * 4;
#pragma unroll
    for (int j = 0; j < 4; ++j) {
      int col = bn + wc + j * 16 + l15;
      float bv = bias[col];
#pragma unroll
      for (int r = 0; r < 4; ++r)
        store_val(&C[(long)(row0 + r) * N + col], acc[i][j][r] + bv);
    }
  }
}

// ---------------------------------------------------------------------------
// RMSNorm rows of q and k (in-place in qkv bf16 buffer), fold softmax scale
// (1/sqrt(hd) * log2e) into q so attention works in exp2 domain.
// One block (256 thr) per row; 8 elems/thread over D=2048.
// ---------------------------------------------------------------------------
__global__ __launch_bounds__(256) void rmsnorm_kernel(
    __bf16* __restrict__ qkv, const float* __restrict__ qw,
    const float* __restrict__ kw) {
  const int r = blockIdx.x;
  const bool isQ = r < BS;
  const int row = isQ ? r : r - BS;
  __bf16* p = qkv + (long)row * N3 + (isQ ? 0 : DD);
  const float* w = isQ ? qw : kw;
  const float extra = isQ ? (0.0883883476483184f * 1.44269504088896f) : 1.0f;
  const int t = threadIdx.x;

  bf16x8 v = *(const bf16x8*)(p + t * 8);
  float f[8];
  float s = 0.f;
#pragma unroll
  for (int i = 0; i < 8; ++i) { f[i] = (float)v[i]; s += f[i] * f[i]; }
#pragma unroll
  for (int off = 32; off > 0; off >>= 1) s += __shfl_xor(s, off, 64);
  __shared__ float red[4];
  if ((t & 63) == 0) red[t >> 6] = s;
  __syncthreads();
  float tot = red[0] + red[1] + red[2] + red[3];
  float rs = rsqrtf(tot * (1.0f / (float)DD) + 1e-6f) * extra;
  bf16x8 o;
#pragma unroll
  for (int i = 0; i < 8; ++i) o[i] = (__bf16)(f[i] * rs * w[t * 8 + i]);
  *(bf16x8*)(p + t * 8) = o;
}

// ---------------------------------------------------------------------------
// transpose v per head: vt[(bh*128+d)*S + s] = qkv[(b*S+s)*3D + 2D + h*128 + d]
// ---------------------------------------------------------------------------
__global__ __launch_bounds__(256) void transpose_v_kernel(
    const __bf16* __restrict__ qkv, __bf16* __restrict__ vt) {
  __shared__ __bf16 t[32][33];
  const int bh = blockIdx.z, b = bh >> 4, h = bh & 15;
  const int s0 = blockIdx.x * 32, d0 = blockIdx.y * 32;
  const int tx = threadIdx.x & 31, ty = threadIdx.x >> 5;
#pragma unroll
  for (int i = 0; i < 4; ++i) {
    int s = s0 + ty + i * 8;
    t[ty + i * 8][tx] =
        qkv[(long)(b * SS + s) * N3 + 2 * DD + h * HD + d0 + tx];
  }
  __syncthreads();
#pragma unroll
  for (int i = 0; i < 4; ++i) {
    int d = d0 + ty + i * 8;
    vt[((long)bh * HD + d) * SS + s0 + tx] = t[tx][ty + i * 8];
  }
}

// ---------------------------------------------------------------------------
// Flash attention, causal. grid (S/64, B*H). block 256 (4 waves).
// Br=Bc=64; wave w owns q-rows [w*16, w*16+16).
// q pre-scaled by 1/sqrt(hd)*log2e -> softmax in exp2 domain.
// ---------------------------------------------------------------------------
__global__ __launch_bounds__(256, 2) void attn_kernel(
    const __bf16* __restrict__ qkv, const __bf16* __restrict__ vt,
    __bf16* __restrict__ O) {
  __shared__ __attribute__((aligned(16))) __bf16 sQ[64 * 128];
  __shared__ __attribute__((aligned(16))) __bf16 sK[64 * 128];
  __shared__ __attribute__((aligned(16))) __bf16 sV[128 * 64];  // [d][k]
  __shared__ __attribute__((aligned(16))) __bf16 sP[4][16 * 72]; // pad 64->72

  const int qi = blockIdx.x, bh = blockIdx.y;
  const int b = bh >> 4, h = bh & 15;
  const int tid = threadIdx.x, wave = tid >> 6, lane = tid & 63;
  const int quad = lane >> 4, l15 = lane & 15;

  const long rowQ0 = (long)(b * SS + qi * 64);
  const __bf16* qbase = qkv + rowQ0 * N3 + h * HD;
  const __bf16* kbase = qkv + (long)(b * SS) * N3 + DD + h * HD;
  const __bf16* vbase = vt + (long)bh * HD * SS;

  // stage Q (64 rows x 128): inst = 4 rows; lane -> row=lane>>4, chunk=l15
  {
    const __bf16* qp = qbase + (long)(wave * 16 + quad) * N3 + l15 * 8;
    __bf16* dst = &sQ[wave * 16 * 128];
#pragma unroll
    for (int t = 0; t < 4; ++t)
      async16(qp + (long)(t * 4) * N3, dst + t * 4 * 128);
  }

  f32x4 o_acc[8] = {};
  float m_run[4], l_run[4];
#pragma unroll
  for (int r = 0; r < 4; ++r) { m_run[r] = -1e30f; l_run[r] = 0.f; }

  for (int j = 0; j <= qi; ++j) {
    __syncthreads();
    {  // stage K tile (64x128)
      const __bf16* kp =
          kbase + (long)(j * 64 + wave * 16 + quad) * N3 + l15 * 8;
      __bf16* dst = &sK[wave * 16 * 128];
#pragma unroll
      for (int t = 0; t < 4; ++t)
        async16(kp + (long)(t * 4) * N3, dst + t * 4 * 128);
    }
    {  // stage V^T tile (128 d-rows x 64): inst = 8 rows; lane->row=lane>>3
      const __bf16* vp = vbase + (long)(wave * 32 + (lane >> 3)) * SS +
                         j * 64 + (lane & 7) * 8;
      __bf16* dst = &sV[wave * 32 * 64];
#pragma unroll
      for (int t = 0; t < 4; ++t)
        async16(vp + (long)(t * 8) * SS, dst + t * 8 * 64);
    }
    __syncthreads();

    // S = Q K^T (already in log2 domain)
    f32x4 sacc[4];
#pragma unroll
    for (int nt = 0; nt < 4; ++nt) {
      sacc[nt] = (f32x4){0.f, 0.f, 0.f, 0.f};
#pragma unroll
      for (int kk = 0; kk < 4; ++kk) {
        bf16x8 aq = *(const bf16x8*)&sQ[(wave * 16 + l15) * 128 + kk * 32 + quad * 8];
        bf16x8 bk = *(const bf16x8*)&sK[(nt * 16 + l15) * 128 + kk * 32 + quad * 8];
        sacc[nt] = __builtin_amdgcn_mfma_f32_16x16x32_bf16(aq, bk, sacc[nt], 0, 0, 0);
      }
    }
    if (j == qi) {  // causal mask inside diagonal tile
#pragma unroll
      for (int nt = 0; nt < 4; ++nt) {
        int coln = nt * 16 + l15;
#pragma unroll
        for (int r = 0; r < 4; ++r)
          if (coln > wave * 16 + quad * 4 + r) sacc[nt][r] = -1e30f;
      }
    }
    // online softmax per row (row = quad*4 + r, spread over 16 lanes)
    float alpha[4], lsum[4];
#pragma unroll
    for (int r = 0; r < 4; ++r) {
      float v = fmaxf(fmaxf(sacc[0][r], sacc[1][r]), fmaxf(sacc[2][r], sacc[3][r]));
#pragma unroll
      for (int off = 1; off < 16; off <<= 1) v = fmaxf(v, __shfl_xor(v, off, 64));
      float mnew = fmaxf(m_run[r], v);
      alpha[r] = exp2f(m_run[r] - mnew);
      m_run[r] = mnew;
      lsum[r] = 0.f;
    }
#pragma unroll
    for (int nt = 0; nt < 4; ++nt) {
#pragma unroll
      for (int r = 0; r < 4; ++r) {
        float pv = exp2f(sacc[nt][r] - m_run[r]);
        lsum[r] += pv;
        sP[wave][(quad * 4 + r) * 72 + nt * 16 + l15] = (__bf16)pv;
      }
    }
#pragma unroll
    for (int r = 0; r < 4; ++r) {
      float v = lsum[r];
#pragma unroll
      for (int off = 1; off < 16; off <<= 1) v += __shfl_xor(v, off, 64);
      l_run[r] = l_run[r] * alpha[r] + v;
    }
#pragma unroll
    for (int dt = 0; dt < 8; ++dt)
#pragma unroll
      for (int r = 0; r < 4; ++r) o_acc[dt][r] *= alpha[r];
    // O += P V  (P strip is wave-private in LDS; compiler orders via lgkmcnt)
#pragma unroll
    for (int dt = 0; dt < 8; ++dt) {
#pragma unroll
      for (int kk = 0; kk < 2; ++kk) {
        bf16x8 ap = *(const bf16x8*)&sP[wave][l15 * 72 + kk * 32 + quad * 8];
        bf16x8 bv = *(const bf16x8*)&sV[(dt * 16 + l15) * 64 + kk * 32 + quad * 8];
        o_acc[dt] = __builtin_amdgcn_mfma_f32_16x16x32_bf16(ap, bv, o_acc[dt], 0, 0, 0);
      }
    }
  }

  // epilogue: O /= l, write [B,S,D] bf16
  __bf16* obase = O + (rowQ0 + wave * 16 + quad * 4) * DD + h * HD;
#pragma unroll
  for (int r = 0; r < 4; ++r) {
    float inv = 1.0f / l_run[r];
#pragma unroll
    for (int dt = 0; dt < 8; ++dt)
      obase[(long)r * DD + dt * 16 + l15] = (__bf16)(o_acc[dt][r] * inv);
  }
}

// ---------------------------------------------------------------------------
// launch
// ---------------------------------------------------------------------------
extern "C" void kernel_launch(void* const* d_in, const int* in_sizes, int n_in,
                              void* d_out, int out_size, void* d_ws,
                              size_t ws_size, hipStream_t stream) {
  const float* x      = (const float*)d_in[0];  // [B,S,D]
  const float* w_qkv  = (const float*)d_in[1];  // [D,3D]
  const float* b_qkv  = (const float*)d_in[2];  // [3D]
  const float* q_ln_w = (const float*)d_in[3];  // [D]
  const float* k_ln_w = (const float*)d_in[4];  // [D]
  const float* w_out  = (const float*)d_in[5];  // [D,D]
  const float* b_out  = (const float*)d_in[6];  // [D]
  float* out = (float*)d_out;                   // [B,S,D] fp32

  // workspace layout (bytes). attn_out aliases x_bf16 (x dead after GEMM1).
  char* w = (char*)d_ws;
  __bf16* xb    = (__bf16*)(w);                 // 12582912 elems (also attn out)
  __bf16* wqkvT = (__bf16*)(w + 25165824L);     // 12582912
  __bf16* woutT = (__bf16*)(w + 50331648L);     // 4194304
  __bf16* qkvb  = (__bf16*)(w + 58720256L);     // 37748736
  __bf16* vtb   = (__bf16*)(w + 134217728L);    // 12582912
  __bf16* atto  = xb;

  // 1. casts / weight transposes
  cast_bf16_kernel<<<dim3(BS * DD / 2048), 256, 0, stream>>>(x, xb);
  transpose_cast_kernel<<<dim3(N3 / 32, DD / 32), 256, 0, stream>>>(
      w_qkv, wqkvT, DD, N3);
  transpose_cast_kernel<<<dim3(DD / 32, DD / 32), 256, 0, stream>>>(
      w_out, woutT, DD, DD);

  // 2. qkv = x @ w_qkv + b  (bf16 out)
  gemm_bt_kernel<__bf16><<<dim3(N3 / 128, BS / 128), 256, 0, stream>>>(
      xb, wqkvT, b_qkv, qkvb, BS, N3, DD);

  // 3. rmsnorm q,k (q also picks up softmax scale * log2e)
  rmsnorm_kernel<<<dim3(2 * BS), 256, 0, stream>>>(qkvb, q_ln_w, k_ln_w);

  // 4. v -> vt[b,h,d,s]
  transpose_v_kernel<<<dim3(SS / 32, HD / 32, BB * HH), 256, 0, stream>>>(
      qkvb, vtb);

  // 5. causal flash attention -> atto [B,S,D] bf16
  attn_kernel<<<dim3(SS / 64, BB * HH), 256, 0, stream>>>(qkvb, vtb, atto);

  // 6. out = atto @ w_out + b_out (fp32 out)
  gemm_bt_kernel<float><<<dim3(DD / 128, BS / 128), 256, 0, stream>>>(
      atto, woutT, b_out, out, BS, DD, DD);
}

// Round 2
// 614.772 us; speedup vs baseline: 1.1373x; 1.1373x over previous
//
#include <hip/hip_runtime.h>
#include <stdint.h>

// Problem constants (B=4, S=1536, D=2048, H=16, hd=128)
#define BB 4
#define SS 1536
#define DD 2048
#define HH 16
#define HD 128
#define BS (BB * SS)        // 6144 rows
#define N3 (3 * DD)         // 6144

typedef __bf16 bf16x8 __attribute__((ext_vector_type(8)));
typedef float f32x4 __attribute__((ext_vector_type(4)));

__device__ __forceinline__ void async16(const void* g, void* lds) {
  __builtin_amdgcn_global_load_lds(
      (const __attribute__((address_space(1))) unsigned int*)g,
      (__attribute__((address_space(3))) unsigned int*)lds, 16, 0, 0);
}

__global__ __launch_bounds__(256) void cast_bf16_kernel(
    const float* __restrict__ in, __bf16* __restrict__ out) {
  long i = ((long)blockIdx.x * 256 + threadIdx.x) * 8;
  float4 a = *(const float4*)(in + i);
  float4 b = *(const float4*)(in + i + 4);
  bf16x8 o;
  o[0] = (__bf16)a.x; o[1] = (__bf16)a.y; o[2] = (__bf16)a.z; o[3] = (__bf16)a.w;
  o[4] = (__bf16)b.x; o[5] = (__bf16)b.y; o[6] = (__bf16)b.z; o[7] = (__bf16)b.w;
  *(bf16x8*)(out + i) = o;
}

__global__ __launch_bounds__(256) void transpose_cast_kernel(
    const float* __restrict__ in, __bf16* __restrict__ out, int R, int C) {
  __shared__ __bf16 t[32][33];
  int tx = threadIdx.x & 31, ty = threadIdx.x >> 5;  // 32 x 8
  long r0 = (long)blockIdx.y * 32, c0 = (long)blockIdx.x * 32;
#pragma unroll
  for (int i = 0; i < 4; ++i)
    t[ty + i * 8][tx] = (__bf16)in[(r0 + ty + i * 8) * C + c0 + tx];
  __syncthreads();
#pragma unroll
  for (int i = 0; i < 4; ++i)
    out[(c0 + ty + i * 8) * R + r0 + tx] = t[tx][ty + i * 8];
}

// ---------------------------------------------------------------------------
// GEMM with XOR-swizzled LDS (chunk c of row r at slot c ^ ((r>>1)&3)).
// ---------------------------------------------------------------------------
__device__ __forceinline__ void store_val(__bf16* p, float v) { *p = (__bf16)v; }
__device__ __forceinline__ void store_val(float* p, float v) { *p = v; }

template <typename OutT>
__global__ __launch_bounds__(256, 2) void gemm_bt_kernel(
    const __bf16* __restrict__ A, const __bf16* __restrict__ Bt,
    const float* __restrict__ bias, OutT* __restrict__ C,
    int M, int N, int K) {
  __shared__ __attribute__((aligned(16))) __bf16 sA[128 * 32];
  __shared__ __attribute__((aligned(16))) __bf16 sB[128 * 32];
  const int tid = threadIdx.x;
  const int wave = tid >> 6, lane = tid & 63;
  const int quad = lane >> 4, l15 = lane & 15;
  const int bm = blockIdx.y * 128, bn = blockIdx.x * 128;
  const int wr = (wave >> 1) * 64, wc = (wave & 1) * 64;

  const int srow = lane >> 2;
  const int scol = ((lane & 3) ^ ((lane >> 3) & 3)) * 8;  // swizzled source
  const __bf16* Ap = A + (long)(bm + wave * 32 + srow) * K + scol;
  const __bf16* Bp = Bt + (long)(bn + wave * 32 + srow) * K + scol;
  __bf16* sAw = &sA[wave * 32 * 32];
  __bf16* sBw = &sB[wave * 32 * 32];

  const int achunk = (quad ^ ((l15 >> 1) & 3)) * 8;  // swizzled frag read

  f32x4 acc[4][4] = {};

  for (int k0 = 0; k0 < K; k0 += 32) {
    __syncthreads();
    async16(Ap + k0, sAw);
    async16(Ap + k0 + (long)16 * K, sAw + 16 * 32);
    async16(Bp + k0, sBw);
    async16(Bp + k0 + (long)16 * K, sBw + 16 * 32);
    __syncthreads();
    bf16x8 af[4], bfr[4];
#pragma unroll
    for (int i = 0; i < 4; ++i)
      af[i] = *(const bf16x8*)&sA[(wr + i * 16 + l15) * 32 + achunk];
#pragma unroll
    for (int i = 0; i < 4; ++i)
      bfr[i] = *(const bf16x8*)&sB[(wc + i * 16 + l15) * 32 + achunk];
#pragma unroll
    for (int i = 0; i < 4; ++i)
#pragma unroll
      for (int j = 0; j < 4; ++j)
        acc[i][j] = __builtin_amdgcn_mfma_f32_16x16x32_bf16(af[i], bfr[j],
                                                            acc[i][j], 0, 0, 0);
  }

#pragma unroll
  for (int i = 0; i < 4; ++i) {
    int row0 = bm + wr + i * 16 + quad * 4;
#pragma unroll
    for (int j = 0; j < 4; ++j) {
      int col = bn + wc + j * 16 + l15;
      float bv = bias[col];
#pragma unroll
      for (int r = 0; r < 4; ++r)
        store_val(&C[(long)(row0 + r) * N + col], acc[i][j][r] + bv);
    }
  }
}

__global__ __launch_bounds__(256) void rmsnorm_kernel(
    __bf16* __restrict__ qkv, const float* __restrict__ qw,
    const float* __restrict__ kw) {
  const int r = blockIdx.x;
  const bool isQ = r < BS;
  const int row = isQ ? r : r - BS;
  __bf16* p = qkv + (long)row * N3 + (isQ ? 0 : DD);
  const float* w = isQ ? qw : kw;
  const float extra = isQ ? (0.0883883476483184f * 1.44269504088896f) : 1.0f;
  const int t = threadIdx.x;

  bf16x8 v = *(const bf16x8*)(p + t * 8);
  float f[8];
  float s = 0.f;
#pragma unroll
  for (int i = 0; i < 8; ++i) { f[i] = (float)v[i]; s += f[i] * f[i]; }
#pragma unroll
  for (int off = 32; off > 0; off >>= 1) s += __shfl_xor(s, off, 64);
  __shared__ float red[4];
  if ((t & 63) == 0) red[t >> 6] = s;
  __syncthreads();
  float tot = red[0] + red[1] + red[2] + red[3];
  float rs = rsqrtf(tot * (1.0f / (float)DD) + 1e-6f) * extra;
  bf16x8 o;
#pragma unroll
  for (int i = 0; i < 8; ++i) o[i] = (__bf16)(f[i] * rs * w[t * 8 + i]);
  *(bf16x8*)(p + t * 8) = o;
}

__global__ __launch_bounds__(256) void transpose_v_kernel(
    const __bf16* __restrict__ qkv, __bf16* __restrict__ vt) {
  __shared__ __bf16 t[32][33];
  const int bh = blockIdx.z, b = bh >> 4, h = bh & 15;
  const int s0 = blockIdx.x * 32, d0 = blockIdx.y * 32;
  const int tx = threadIdx.x & 31, ty = threadIdx.x >> 5;
#pragma unroll
  for (int i = 0; i < 4; ++i) {
    int s = s0 + ty + i * 8;
    t[ty + i * 8][tx] =
        qkv[(long)(b * SS + s) * N3 + 2 * DD + h * HD + d0 + tx];
  }
  __syncthreads();
#pragma unroll
  for (int i = 0; i < 4; ++i) {
    int d = d0 + ty + i * 8;
    vt[((long)bh * HD + d) * SS + s0 + tx] = t[tx][ty + i * 8];
  }
}

// ---------------------------------------------------------------------------
// Flash attention, causal. grid (S/64, B*H), 4 waves. Q frags in registers.
// sK: 64x128, chunk slot = c ^ (row&7). sV: 128x64 [d][k], slot = c ^ (row&7).
// sP: per-wave 16x64, same swizzle.  q pre-scaled by 1/sqrt(hd)*log2e.
// NOTE async16 LDS dest must be wave-uniform: each inst's dst base depends
// only on (wave, t); lane's row offset comes from lane*16 within the inst.
// ---------------------------------------------------------------------------
__global__ __launch_bounds__(256, 4) void attn_kernel(
    const __bf16* __restrict__ qkv, const __bf16* __restrict__ vt,
    __bf16* __restrict__ O) {
  __shared__ __attribute__((aligned(16))) __bf16 sK[64 * 128];   // 16 KB
  __shared__ __attribute__((aligned(16))) __bf16 sV[128 * 64];   // 16 KB
  __shared__ __attribute__((aligned(16))) __bf16 sP[4][16 * 64]; //  8 KB

  const int qi = blockIdx.x, bh = blockIdx.y;
  const int b = bh >> 4, h = bh & 15;
  const int tid = threadIdx.x, wave = tid >> 6, lane = tid & 63;
  const int quad = lane >> 4, l15 = lane & 15;
  const int sw3 = l15 & 7;

  const long rowQ0 = (long)(b * SS + qi * 64);
  const __bf16* kbase = qkv + (long)(b * SS) * N3 + DD + h * HD;
  const __bf16* vbase = vt + (long)bh * HD * SS;

  // Q fragments in registers
  bf16x8 qf[4];
  {
    const __bf16* qp =
        qkv + (rowQ0 + wave * 16 + l15) * N3 + h * HD + quad * 8;
#pragma unroll
    for (int kk = 0; kk < 4; ++kk) qf[kk] = *(const bf16x8*)(qp + kk * 32);
  }

  f32x4 o_acc[8] = {};
  float m_run[4], l_run[4];
#pragma unroll
  for (int r = 0; r < 4; ++r) { m_run[r] = -1e30f; l_run[r] = 0.f; }

  __bf16* sPw = &sP[wave][0];

  for (int j = 0; j <= qi; ++j) {
    __syncthreads();
    {  // stage K: inst t covers rows [wave*16+t*4, +4); lane row = base+quad,
       // slot = l15, source chunk = l15 ^ (row&7)
#pragma unroll
      for (int t = 0; t < 4; ++t) {
        int rbase = wave * 16 + t * 4;  // wave-uniform
        int row = rbase + quad;
        const __bf16* src =
            kbase + (long)(j * 64 + row) * N3 + ((l15 ^ (row & 7)) * 8);
        async16(src, &sK[rbase * 128]);
      }
    }
    {  // stage V^T: inst t covers rows [wave*32+t*8, +8); lane row = base+(lane>>3)
#pragma unroll
      for (int t = 0; t < 4; ++t) {
        int rbase = wave * 32 + t * 8;  // wave-uniform
        int row = rbase + (lane >> 3);
        const __bf16* src = vbase + (long)row * SS + j * 64 +
                            (((lane & 7) ^ (row & 7)) * 8);
        async16(src, &sV[rbase * 64]);
      }
    }
    __syncthreads();

    // S = Q K^T
    f32x4 sacc[4];
#pragma unroll
    for (int nt = 0; nt < 4; ++nt) {
      sacc[nt] = (f32x4){0.f, 0.f, 0.f, 0.f};
#pragma unroll
      for (int kk = 0; kk < 4; ++kk) {
        bf16x8 bk = *(const bf16x8*)
            &sK[(nt * 16 + l15) * 128 + (((kk * 4 + quad) ^ sw3) * 8)];
        sacc[nt] = __builtin_amdgcn_mfma_f32_16x16x32_bf16(qf[kk], bk, sacc[nt], 0, 0, 0);
      }
    }
    if (j == qi) {
#pragma unroll
      for (int nt = 0; nt < 4; ++nt) {
        int coln = nt * 16 + l15;
#pragma unroll
        for (int r = 0; r < 4; ++r)
          if (coln > wave * 16 + quad * 4 + r) sacc[nt][r] = -1e30f;
      }
    }
    float alpha[4], lsum[4];
#pragma unroll
    for (int r = 0; r < 4; ++r) {
      float v = fmaxf(fmaxf(sacc[0][r], sacc[1][r]), fmaxf(sacc[2][r], sacc[3][r]));
#pragma unroll
      for (int off = 1; off < 16; off <<= 1) v = fmaxf(v, __shfl_xor(v, off, 64));
      float mnew = fmaxf(m_run[r], v);
      alpha[r] = exp2f(m_run[r] - mnew);
      m_run[r] = mnew;
      lsum[r] = 0.f;
    }
#pragma unroll
    for (int nt = 0; nt < 4; ++nt) {
#pragma unroll
      for (int r = 0; r < 4; ++r) {
        float pv = exp2f(sacc[nt][r] - m_run[r]);
        lsum[r] += pv;
        int prow = quad * 4 + r;
        int pcol = nt * 16 + l15;
        sPw[prow * 64 + (((pcol >> 3) ^ (prow & 7)) * 8) + (pcol & 7)] =
            (__bf16)pv;
      }
    }
#pragma unroll
    for (int r = 0; r < 4; ++r) {
      float v = lsum[r];
#pragma unroll
      for (int off = 1; off < 16; off <<= 1) v += __shfl_xor(v, off, 64);
      l_run[r] = l_run[r] * alpha[r] + v;
    }
#pragma unroll
    for (int dt = 0; dt < 8; ++dt)
#pragma unroll
      for (int r = 0; r < 4; ++r) o_acc[dt][r] *= alpha[r];
#pragma unroll
    for (int dt = 0; dt < 8; ++dt) {
#pragma unroll
      for (int kk = 0; kk < 2; ++kk) {
        bf16x8 ap = *(const bf16x8*)
            &sPw[l15 * 64 + (((kk * 4 + quad) ^ sw3) * 8)];
        bf16x8 bv = *(const bf16x8*)
            &sV[(dt * 16 + l15) * 64 + (((kk * 4 + quad) ^ sw3) * 8)];
        o_acc[dt] = __builtin_amdgcn_mfma_f32_16x16x32_bf16(ap, bv, o_acc[dt], 0, 0, 0);
      }
    }
  }

  __bf16* obase = O + (rowQ0 + wave * 16 + quad * 4) * DD + h * HD;
#pragma unroll
  for (int r = 0; r < 4; ++r) {
    float inv = 1.0f / l_run[r];
#pragma unroll
    for (int dt = 0; dt < 8; ++dt)
      obase[(long)r * DD + dt * 16 + l15] = (__bf16)(o_acc[dt][r] * inv);
  }
}

extern "C" void kernel_launch(void* const* d_in, const int* in_sizes, int n_in,
                              void* d_out, int out_size, void* d_ws,
                              size_t ws_size, hipStream_t stream) {
  const float* x      = (const float*)d_in[0];
  const float* w_qkv  = (const float*)d_in[1];
  const float* b_qkv  = (const float*)d_in[2];
  const float* q_ln_w = (const float*)d_in[3];
  const float* k_ln_w = (const float*)d_in[4];
  const float* w_out  = (const float*)d_in[5];
  const float* b_out  = (const float*)d_in[6];
  float* out = (float*)d_out;

  char* w = (char*)d_ws;
  __bf16* xb    = (__bf16*)(w);
  __bf16* wqkvT = (__bf16*)(w + 25165824L);
  __bf16* woutT = (__bf16*)(w + 50331648L);
  __bf16* qkvb  = (__bf16*)(w + 58720256L);
  __bf16* vtb   = (__bf16*)(w + 134217728L);
  __bf16* atto  = xb;

  cast_bf16_kernel<<<dim3(BS * DD / 2048), 256, 0, stream>>>(x, xb);
  transpose_cast_kernel<<<dim3(N3 / 32, DD / 32), 256, 0, stream>>>(
      w_qkv, wqkvT, DD, N3);
  transpose_cast_kernel<<<dim3(DD / 32, DD / 32), 256, 0, stream>>>(
      w_out, woutT, DD, DD);

  gemm_bt_kernel<__bf16><<<dim3(N3 / 128, BS / 128), 256, 0, stream>>>(
      xb, wqkvT, b_qkv, qkvb, BS, N3, DD);

  rmsnorm_kernel<<<dim3(2 * BS), 256, 0, stream>>>(qkvb, q_ln_w, k_ln_w);

  transpose_v_kernel<<<dim3(SS / 32, HD / 32, BB * HH), 256, 0, stream>>>(
      qkvb, vtb);

  attn_kernel<<<dim3(SS / 64, BB * HH), 256, 0, stream>>>(qkvb, vtb, atto);

  gemm_bt_kernel<float><<<dim3(DD / 128, BS / 128), 256, 0, stream>>>(
      atto, woutT, b_out, out, BS, DD, DD);
}